// Round 1
// baseline (280.323 us; speedup 1.0000x reference)
//
#include <hip/hip_runtime.h>
#include <stdint.h>

#define B_  16
#define C_  512
#define T_  1024
#define NH_ 8
#define O3_ 1536

typedef __bf16 bf16_t;
typedef bf16_t bf16x8 __attribute__((ext_vector_type(8)));
typedef float  f32x4  __attribute__((ext_vector_type(4)));
typedef unsigned short u16;

__device__ inline u16 f2bf(float f) {
    union { float f; unsigned u; } v; v.f = f;
    unsigned r = v.u + 0x7FFF + ((v.u >> 16) & 1);
    return (u16)(r >> 16);
}

// ---------------- weight convert ----------------
__global__ __launch_bounds__(256) void k_convert(const float* __restrict__ wq,
                                                 const float* __restrict__ wp,
                                                 u16* __restrict__ wq_b,
                                                 u16* __restrict__ wp_b) {
    int i = blockIdx.x * 256 + threadIdx.x;
    const int nq = O3_ * C_;           // 786432
    if (i < nq) wq_b[i] = f2bf(wq[i]);
    else        wp_b[i - nq] = f2bf(wp[i - nq]);
}

// ---------------- GroupNorm -> h (t-major bf16) ----------------
__global__ __launch_bounds__(256) void k_gn(const float* __restrict__ x,
                                            const float* __restrict__ gsc,
                                            const float* __restrict__ gbi,
                                            u16* __restrict__ h_t) {
    __shared__ float red[8];
    int b = blockIdx.x >> 5, g = blockIdx.x & 31;
    int tid = threadIdx.x;
    const float4* src = (const float4*)(x + ((size_t)(b * C_ + g * 16)) * T_);
    float4 v[16];
    float s = 0.f, q = 0.f;
#pragma unroll
    for (int i = 0; i < 16; ++i) {
        v[i] = src[i * 256 + tid];
        s += v[i].x + v[i].y + v[i].z + v[i].w;
        q += v[i].x * v[i].x + v[i].y * v[i].y + v[i].z * v[i].z + v[i].w * v[i].w;
    }
#pragma unroll
    for (int m = 32; m; m >>= 1) { s += __shfl_xor(s, m); q += __shfl_xor(q, m); }
    int w = tid >> 6;
    if ((tid & 63) == 0) { red[w] = s; red[4 + w] = q; }
    __syncthreads();
    s = red[0] + red[1] + red[2] + red[3];
    q = red[4] + red[5] + red[6] + red[7];
    float mean = s * (1.f / 16384.f);
    float var  = q * (1.f / 16384.f) - mean * mean;
    float rstd = rsqrtf(var + 1e-5f);
    float sc[16], bi[16];
#pragma unroll
    for (int cc = 0; cc < 16; ++cc) {
        float gam = gsc[g * 16 + cc] * rstd;
        sc[cc] = gam;
        bi[cc] = gbi[g * 16 + cc] - mean * gam;
    }
    // thread owns t = tid*4+j for j=0..3, all 16 channels of the group
#pragma unroll
    for (int j = 0; j < 4; ++j) {
        int t = tid * 4 + j;
        union { uint4 v4[2]; u16 u[16]; } ob;
#pragma unroll
        for (int cc = 0; cc < 16; ++cc) {
            float val = (&v[cc].x)[j];
            ob.u[cc] = f2bf(val * sc[cc] + bi[cc]);
        }
        uint4* dst = (uint4*)(h_t + ((size_t)(b * T_ + t)) * C_ + g * 16);
        dst[0] = ob.v4[0];
        dst[1] = ob.v4[1];
    }
}

// ---------------- QKV GEMM: qkv_t[b][t][o] = sum_c h[t][c]*W[o][c] + bq[o] ----------------
__global__ __launch_bounds__(256) void k_qkv(const u16* __restrict__ h_t,
                                             const u16* __restrict__ wq_b,
                                             const float* __restrict__ bq,
                                             u16* __restrict__ qkv_t) {
    __shared__ __align__(16) u16 la[128 * 40];   // t rows x k
    __shared__ __align__(16) u16 lb[128 * 40];   // o rows x k
    int ob = blockIdx.x, tb = blockIdx.y, b = blockIdx.z;
    int tid = threadIdx.x, lane = tid & 63, w = tid >> 6;
    int wm = w >> 1, wn = w & 1;
    int t0 = tb * 128, o0 = ob * 128;
    const u16* srcA = h_t + ((size_t)b * T_ + t0) * C_;
    const u16* srcB = wq_b + (size_t)o0 * C_;
    int rowA = tid >> 2, kcol = (tid & 3) * 8;
    f32x4 acc[4][4] = {};
    for (int k0 = 0; k0 < C_; k0 += 32) {
        __syncthreads();
        *(uint4*)&la[rowA * 40 + kcol]        = *(const uint4*)&srcA[(size_t)rowA * C_ + k0 + kcol];
        *(uint4*)&la[(rowA + 64) * 40 + kcol] = *(const uint4*)&srcA[(size_t)(rowA + 64) * C_ + k0 + kcol];
        *(uint4*)&lb[rowA * 40 + kcol]        = *(const uint4*)&srcB[(size_t)rowA * C_ + k0 + kcol];
        *(uint4*)&lb[(rowA + 64) * 40 + kcol] = *(const uint4*)&srcB[(size_t)(rowA + 64) * C_ + k0 + kcol];
        __syncthreads();
        bf16x8 af[4], bfr[4];
        int rA = wm * 64 + (lane & 15);
        int rB = wn * 64 + (lane & 15);
        int kk = (lane >> 4) * 8;
#pragma unroll
        for (int m = 0; m < 4; ++m) af[m]  = *(const bf16x8*)&la[(rA + m * 16) * 40 + kk];
#pragma unroll
        for (int n = 0; n < 4; ++n) bfr[n] = *(const bf16x8*)&lb[(rB + n * 16) * 40 + kk];
#pragma unroll
        for (int m = 0; m < 4; ++m)
#pragma unroll
            for (int n = 0; n < 4; ++n)
                acc[m][n] = __builtin_amdgcn_mfma_f32_16x16x32_bf16(af[m], bfr[n], acc[m][n], 0, 0, 0);
    }
    int r0 = (lane >> 4) * 4;
#pragma unroll
    for (int n = 0; n < 4; ++n) {
        int o = o0 + wn * 64 + n * 16 + (lane & 15);
        float bqv = bq[o];
#pragma unroll
        for (int m = 0; m < 4; ++m) {
#pragma unroll
            for (int r = 0; r < 4; ++r) {
                int t = t0 + wm * 64 + m * 16 + r0 + r;
                qkv_t[((size_t)b * T_ + t) * O3_ + o] = f2bf(acc[m][n][r] + bqv);
            }
        }
    }
}

// ---------------- Flash attention ----------------
__global__ __launch_bounds__(256) void k_attn(const u16* __restrict__ qkv_t,
                                              u16* __restrict__ a_t) {
    __shared__ __align__(16) u16 p_lds[4 * 16 * 72];
    __shared__ __align__(16) u16 v_lds[64 * 72];
    int bh = blockIdx.x, tb = blockIdx.y;
    int b = bh >> 3, h = bh & 7;
    int tid = threadIdx.x, lane = tid & 63, w = tid >> 6;
    int t0 = tb * 64;
    const u16* base = qkv_t + (size_t)b * T_ * O3_;
    int qoff = h * 192, koff = qoff + 64, voff = qoff + 128;
    int kk = (lane >> 4) * 8;
    bf16x8 aq0, aq1;
    {
        int t = t0 + w * 16 + (lane & 15);
        aq0 = *(const bf16x8*)&base[(size_t)t * O3_ + qoff + kk];
        aq1 = *(const bf16x8*)&base[(size_t)t * O3_ + qoff + 32 + kk];
    }
    f32x4 o_acc[4] = {};
    float mrun[4], lrun[4];
#pragma unroll
    for (int r = 0; r < 4; ++r) { mrun[r] = -1e30f; lrun[r] = 0.f; }

    for (int s0 = 0; s0 < T_; s0 += 64) {
        f32x4 s_acc[4];
#pragma unroll
        for (int ns = 0; ns < 4; ++ns) {
            int srow = s0 + ns * 16 + (lane & 15);
            bf16x8 bk0 = *(const bf16x8*)&base[(size_t)srow * O3_ + koff + kk];
            bf16x8 bk1 = *(const bf16x8*)&base[(size_t)srow * O3_ + koff + 32 + kk];
            f32x4 z = {};
            z = __builtin_amdgcn_mfma_f32_16x16x32_bf16(aq0, bk0, z, 0, 0, 0);
            z = __builtin_amdgcn_mfma_f32_16x16x32_bf16(aq1, bk1, z, 0, 0, 0);
            s_acc[ns] = z * 0.125f;   // scale^2 = 1/sqrt(ch)
        }
        float p[4][4], alpha[4];
#pragma unroll
        for (int r = 0; r < 4; ++r) {
            float mx = fmaxf(fmaxf(s_acc[0][r], s_acc[1][r]), fmaxf(s_acc[2][r], s_acc[3][r]));
#pragma unroll
            for (int msk = 8; msk; msk >>= 1) mx = fmaxf(mx, __shfl_xor(mx, msk));
            float mnew = fmaxf(mrun[r], mx);
            alpha[r] = __expf(mrun[r] - mnew);
            mrun[r] = mnew;
            float sum = 0.f;
#pragma unroll
            for (int ns = 0; ns < 4; ++ns) { p[ns][r] = __expf(s_acc[ns][r] - mnew); sum += p[ns][r]; }
#pragma unroll
            for (int msk = 8; msk; msk >>= 1) sum += __shfl_xor(sum, msk);
            lrun[r] = lrun[r] * alpha[r] + sum;
        }
#pragma unroll
        for (int nc = 0; nc < 4; ++nc)
#pragma unroll
            for (int r = 0; r < 4; ++r) o_acc[nc][r] *= alpha[r];
        // write P tile (C/D layout -> LDS, re-read in A layout)
        int prow0 = (lane >> 4) * 4;
#pragma unroll
        for (int ns = 0; ns < 4; ++ns)
#pragma unroll
            for (int r = 0; r < 4; ++r)
                p_lds[w * 1152 + (prow0 + r) * 72 + ns * 16 + (lane & 15)] = f2bf(p[ns][r]);
        __syncthreads();
        // stage V^T cooperatively
#pragma unroll
        for (int it = 0; it < 2; ++it) {
            int task = it * 256 + tid;
            int s = task >> 3, cb = (task & 7) * 8;
            union { uint4 v4; u16 u[8]; } tv;
            tv.v4 = *(const uint4*)&base[(size_t)(s0 + s) * O3_ + voff + cb];
#pragma unroll
            for (int j = 0; j < 8; ++j) v_lds[(cb + j) * 72 + s] = tv.u[j];
        }
        __syncthreads();
        bf16x8 pa0 = *(const bf16x8*)&p_lds[w * 1152 + (lane & 15) * 72 + kk];
        bf16x8 pa1 = *(const bf16x8*)&p_lds[w * 1152 + (lane & 15) * 72 + 32 + kk];
#pragma unroll
        for (int nc = 0; nc < 4; ++nc) {
            bf16x8 vb0 = *(const bf16x8*)&v_lds[(nc * 16 + (lane & 15)) * 72 + kk];
            bf16x8 vb1 = *(const bf16x8*)&v_lds[(nc * 16 + (lane & 15)) * 72 + 32 + kk];
            o_acc[nc] = __builtin_amdgcn_mfma_f32_16x16x32_bf16(pa0, vb0, o_acc[nc], 0, 0, 0);
            o_acc[nc] = __builtin_amdgcn_mfma_f32_16x16x32_bf16(pa1, vb1, o_acc[nc], 0, 0, 0);
        }
    }
#pragma unroll
    for (int nc = 0; nc < 4; ++nc) {
        int c = h * 64 + nc * 16 + (lane & 15);
#pragma unroll
        for (int r = 0; r < 4; ++r) {
            int t = t0 + w * 16 + (lane >> 4) * 4 + r;
            a_t[((size_t)b * T_ + t) * C_ + c] = f2bf(o_acc[nc][r] / lrun[r]);
        }
    }
}

// ---------------- Proj GEMM + bias + residual: out[b][o][t] ----------------
__global__ __launch_bounds__(256) void k_proj(const u16* __restrict__ a_t,
                                              const u16* __restrict__ wp_b,
                                              const float* __restrict__ bp,
                                              const float* __restrict__ x,
                                              float* __restrict__ out) {
    __shared__ __align__(16) u16 la[128 * 40];   // o rows x k
    __shared__ __align__(16) u16 lb[128 * 40];   // t rows x k
    int tb = blockIdx.x, ob = blockIdx.y, b = blockIdx.z;
    int tid = threadIdx.x, lane = tid & 63, w = tid >> 6;
    int wm = w >> 1, wn = w & 1;
    int o0 = ob * 128, t0 = tb * 128;
    const u16* srcA = wp_b + (size_t)o0 * C_;
    const u16* srcB = a_t + ((size_t)b * T_ + t0) * C_;
    int rowA = tid >> 2, kcol = (tid & 3) * 8;
    f32x4 acc[4][4] = {};
    for (int k0 = 0; k0 < C_; k0 += 32) {
        __syncthreads();
        *(uint4*)&la[rowA * 40 + kcol]        = *(const uint4*)&srcA[(size_t)rowA * C_ + k0 + kcol];
        *(uint4*)&la[(rowA + 64) * 40 + kcol] = *(const uint4*)&srcA[(size_t)(rowA + 64) * C_ + k0 + kcol];
        *(uint4*)&lb[rowA * 40 + kcol]        = *(const uint4*)&srcB[(size_t)rowA * C_ + k0 + kcol];
        *(uint4*)&lb[(rowA + 64) * 40 + kcol] = *(const uint4*)&srcB[(size_t)(rowA + 64) * C_ + k0 + kcol];
        __syncthreads();
        bf16x8 af[4], bfr[4];
        int rA = wm * 64 + (lane & 15);
        int rB = wn * 64 + (lane & 15);
        int kk = (lane >> 4) * 8;
#pragma unroll
        for (int m = 0; m < 4; ++m) af[m]  = *(const bf16x8*)&la[(rA + m * 16) * 40 + kk];
#pragma unroll
        for (int n = 0; n < 4; ++n) bfr[n] = *(const bf16x8*)&lb[(rB + n * 16) * 40 + kk];
#pragma unroll
        for (int m = 0; m < 4; ++m)
#pragma unroll
            for (int n = 0; n < 4; ++n)
                acc[m][n] = __builtin_amdgcn_mfma_f32_16x16x32_bf16(af[m], bfr[n], acc[m][n], 0, 0, 0);
    }
    int r0 = (lane >> 4) * 4;
#pragma unroll
    for (int m = 0; m < 4; ++m) {
#pragma unroll
        for (int r = 0; r < 4; ++r) {
            int o = o0 + wm * 64 + m * 16 + r0 + r;
            float bpv = bp[o];
            const float* xrow = x + ((size_t)b * C_ + o) * T_;
            float* orow = out + ((size_t)b * C_ + o) * T_;
#pragma unroll
            for (int n = 0; n < 4; ++n) {
                int t = t0 + wn * 64 + n * 16 + (lane & 15);
                orow[t] = acc[m][n][r] + bpv + xrow[t];
            }
        }
    }
}

extern "C" void kernel_launch(void* const* d_in, const int* in_sizes, int n_in,
                              void* d_out, int out_size, void* d_ws, size_t ws_size,
                              hipStream_t stream) {
    (void)in_sizes; (void)n_in; (void)out_size; (void)ws_size;
    const float* x   = (const float*)d_in[0];
    const float* gsc = (const float*)d_in[1];
    const float* gbi = (const float*)d_in[2];
    const float* wq  = (const float*)d_in[3];
    const float* bq  = (const float*)d_in[4];
    const float* wp  = (const float*)d_in[5];
    const float* bp  = (const float*)d_in[6];
    float* out = (float*)d_out;
    char* ws = (char*)d_ws;

    u16* wq_b  = (u16*)(ws);                    // 1536*512*2      = 1572864
    u16* wp_b  = (u16*)(ws + 1572864);          // 512*512*2       =  524288
    u16* h_t   = (u16*)(ws + 2097152);          // 16*1024*512*2   = 16777216
    u16* qkv_t = (u16*)(ws + 18874368);         // 16*1024*1536*2  = 50331648
    u16* a_t   = h_t;                           // reuse h_t region after qkv GEMM

    k_convert<<<dim3(4096), dim3(256), 0, stream>>>(wq, wp, wq_b, wp_b);
    k_gn<<<dim3(B_ * 32), dim3(256), 0, stream>>>(x, gsc, gbi, h_t);
    k_qkv<<<dim3(12, 8, B_), dim3(256), 0, stream>>>(h_t, wq_b, bq, qkv_t);
    k_attn<<<dim3(B_ * NH_, 16), dim3(256), 0, stream>>>(qkv_t, a_t);
    k_proj<<<dim3(8, 4, B_), dim3(256), 0, stream>>>(a_t, wp_b, bp, x, out);
}